// Round 5
// baseline (542.725 us; speedup 1.0000x reference)
//
#include <hip/hip_runtime.h>
#include <hip/hip_bf16.h>
#include <cstdint>
#include <cstddef>

#define LRELU(x, s) ((x) > 0.f ? (x) : (s) * (x))

typedef __attribute__((ext_vector_type(8))) short bf16x8;
typedef __attribute__((ext_vector_type(4))) float f32x4;

__device__ __forceinline__ float bflo(uint v) { return __uint_as_float(v << 16); }
__device__ __forceinline__ float bfhi(uint v) { return __uint_as_float(v & 0xffff0000u); }
__device__ __forceinline__ ushort f2bf(float f) {  // RTNE, finite inputs
  const uint u = __float_as_uint(f);
  return (ushort)((u + 0x7fffu + ((u >> 16) & 1u)) >> 16);
}

// async global->LDS copy, 16 B per lane; LDS dest = wave-uniform base + lane*16.
__device__ __forceinline__ void async16(const ushort* g, ushort* l) {
  __builtin_amdgcn_global_load_lds(
      (const __attribute__((address_space(1))) unsigned int*)g,
      (__attribute__((address_space(3))) unsigned int*)l, 16, 0, 0);
}

// ---------------- casts ----------------
__global__ void cast_pad_rows(const float* __restrict__ in, ushort* __restrict__ out,
                              int rows, int K, int Kp) {
  const int P4 = Kp >> 2;
  const long long idx = (long long)blockIdx.x * blockDim.x + threadIdx.x;
  if (idx >= (long long)rows * P4) return;
  const int r = (int)(idx / P4);
  const int c = ((int)(idx - (long long)r * P4)) << 2;
  const float* p = in + (size_t)r * K + c;
  float v0 = 0.f, v1 = 0.f, v2 = 0.f, v3 = 0.f;
  if (c + 3 < K) { v0 = p[0]; v1 = p[1]; v2 = p[2]; v3 = p[3]; }
  else {
    if (c + 0 < K) v0 = p[0];
    if (c + 1 < K) v1 = p[1];
    if (c + 2 < K) v2 = p[2];
    if (c + 3 < K) v3 = p[3];
  }
  uint2 o;
  o.x = (uint)f2bf(v0) | ((uint)f2bf(v1) << 16);
  o.y = (uint)f2bf(v2) | ((uint)f2bf(v3) << 16);
  *(uint2*)(out + (size_t)r * Kp + c) = o;
}

__global__ void cast_W_T(const float* __restrict__ W, ushort* __restrict__ Wt,
                         int K, int Nn, int Kp) {
  __shared__ float tile[32][33];
  const int kt = blockIdx.x * 32;
  const int nt = blockIdx.y * 32;
  const int tx = threadIdx.x;
  const int ty = threadIdx.y;
  for (int r = ty; r < 32; r += 8) {
    const int k = kt + r, nn = nt + tx;
    tile[r][tx] = (k < K && nn < Nn) ? W[(size_t)k * Nn + nn] : 0.f;
  }
  __syncthreads();
  for (int r = ty; r < 32; r += 8) {
    const int nn = nt + r, k = kt + tx;
    if (nn < Nn && k < Kp) Wt[(size_t)nn * Kp + k] = f2bf(tile[tx][r]);
  }
}

// ---------------- bf16 MFMA GEMM + fused attention-dot epilogue ----------------
// C[M,N] bf16 = A[M,Kp] @ Bt[N,Kp]^T; staging via global_load_lds width=16.
__global__ __launch_bounds__(256) void gemm_bf16(
    const ushort* __restrict__ A, const ushort* __restrict__ Bt, ushort* __restrict__ C,
    int M, int N, int Kp,
    const float* __restrict__ AS, const float* __restrict__ AD,
    float* __restrict__ asb, float* __restrict__ adb, int H, int headC) {
  __shared__ ushort sA[128 * 32];
  __shared__ ushort sB[128 * 32];
  const int tid = threadIdx.x;
  const int wave = tid >> 6;
  const int lane = tid & 63;
  const int tilesN = N >> 7;
  const int bx = blockIdx.x % tilesN;
  const int by = blockIdx.x / tilesN;
  const int wrow = (wave >> 1) * 64;
  const int wcol = (wave & 1) * 64;
  const int quad = lane >> 4;
  const int ml = lane & 15;

  // staging map: wave w covers tile rows [w*32, w*32+32) in two 16-row calls.
  const int r0 = wave * 32 + (lane >> 2);   // rows for call 0
  const int r1 = r0 + 16;                   // rows for call 1
  const int seg = (lane & 3) * 8;           // ushort k-offset within BK=32
  const int gA0 = min(by * 128 + r0, M - 1);
  const int gA1 = min(by * 128 + r1, M - 1);
  const int gB0 = bx * 128 + r0;
  const int gB1 = bx * 128 + r1;
  const ushort* pA0 = A + (size_t)gA0 * Kp + seg;
  const ushort* pA1 = A + (size_t)gA1 * Kp + seg;
  const ushort* pB0 = Bt + (size_t)gB0 * Kp + seg;
  const ushort* pB1 = Bt + (size_t)gB1 * Kp + seg;
  ushort* lA0 = &sA[(wave * 32) * 32];
  ushort* lA1 = &sA[(wave * 32 + 16) * 32];
  ushort* lB0 = &sB[(wave * 32) * 32];
  ushort* lB1 = &sB[(wave * 32 + 16) * 32];

  f32x4 acc[4][4];
#pragma unroll
  for (int mi = 0; mi < 4; mi++)
#pragma unroll
    for (int ni = 0; ni < 4; ni++)
#pragma unroll
      for (int e = 0; e < 4; e++) acc[mi][ni][e] = 0.f;

  for (int k0 = 0; k0 < Kp; k0 += 32) {
    __syncthreads();  // previous iter's ds_reads complete before overwrite
    async16(pA0 + k0, lA0);
    async16(pA1 + k0, lA1);
    async16(pB0 + k0, lB0);
    async16(pB1 + k0, lB1);
    __syncthreads();  // drains vmcnt -> LDS data visible
    bf16x8 af[4], bfr[4];
#pragma unroll
    for (int mi = 0; mi < 4; mi++)
      af[mi] = *(const bf16x8*)&sA[(wrow + mi * 16 + ml) * 32 + quad * 8];
#pragma unroll
    for (int ni = 0; ni < 4; ni++)
      bfr[ni] = *(const bf16x8*)&sB[(wcol + ni * 16 + ml) * 32 + quad * 8];
#pragma unroll
    for (int mi = 0; mi < 4; mi++)
#pragma unroll
      for (int ni = 0; ni < 4; ni++)
        acc[mi][ni] = __builtin_amdgcn_mfma_f32_16x16x32_bf16(af[mi], bfr[ni], acc[mi][ni], 0, 0, 0);
  }

  // C write (bf16)
#pragma unroll
  for (int mi = 0; mi < 4; mi++) {
#pragma unroll
    for (int r = 0; r < 4; r++) {
      const int row = by * 128 + wrow + mi * 16 + quad * 4 + r;
      if (row < M) {
#pragma unroll
        for (int ni = 0; ni < 4; ni++) {
          const int col = bx * 128 + wcol + ni * 16 + ml;
          C[(size_t)row * N + col] = f2bf(acc[mi][ni][r]);
        }
      }
    }
  }

  // fused attention dots
  if (asb != nullptr) {
    float asv[4], adv[4];
#pragma unroll
    for (int ni = 0; ni < 4; ni++) {
      const int col = bx * 128 + wcol + ni * 16 + ml;
      asv[ni] = AS[col];
      adv[ni] = AD[col];
    }
    const int hh = (bx * 128 + wcol) / headC;  // wave-uniform (64-col span <= headC)
#pragma unroll
    for (int mi = 0; mi < 4; mi++) {
#pragma unroll
      for (int r = 0; r < 4; r++) {
        float ps = acc[mi][0][r] * asv[0] + acc[mi][1][r] * asv[1] +
                   acc[mi][2][r] * asv[2] + acc[mi][3][r] * asv[3];
        float pd = acc[mi][0][r] * adv[0] + acc[mi][1][r] * adv[1] +
                   acc[mi][2][r] * adv[2] + acc[mi][3][r] * adv[3];
#pragma unroll
        for (int off = 1; off < 16; off <<= 1) {
          ps += __shfl_xor(ps, off);
          pd += __shfl_xor(pd, off);
        }
        if (ml == 0) {
          const int row = by * 128 + wrow + mi * 16 + quad * 4 + r;
          if (row < M) {
            atomicAdd(&asb[row * H + hh], ps);
            atomicAdd(&adb[row * H + hh], pd);
          }
        }
      }
    }
  }
}

// ---------------- CSR build ----------------
__global__ void count_deg(const int* __restrict__ dst, int E, int* __restrict__ deg) {
  const int t = blockIdx.x * blockDim.x + threadIdx.x;
  if (t < E) atomicAdd(&deg[dst[t]], 1);
}

__global__ __launch_bounds__(1024) void scan_kernel(const int* __restrict__ deg,
                                                    int* __restrict__ rowptr,
                                                    int* __restrict__ cursor, int n) {
  __shared__ int swsum[16];
  __shared__ int carry_s;
  const int t = threadIdx.x;
  const int wv = t >> 6, lane = t & 63;
  if (t == 0) carry_s = 0;
  __syncthreads();
  for (int base = 0; base < n; base += 1024) {
    const int i = base + t;
    const int v = (i < n) ? (deg[i] + 1) : 0;
    int sc = v;
#pragma unroll
    for (int off = 1; off < 64; off <<= 1) {
      const int u = __shfl_up(sc, off);
      if (lane >= off) sc += u;
    }
    if (lane == 63) swsum[wv] = sc;
    __syncthreads();
    if (t < 16) {
      int x = swsum[t];
#pragma unroll
      for (int off = 1; off < 16; off <<= 1) {
        const int u = __shfl_up(x, off);
        if (t >= off) x += u;
      }
      swsum[t] = x;
    }
    __syncthreads();
    const int incl = sc + (wv == 0 ? 0 : swsum[wv - 1]) + carry_s;
    if (i < n) { rowptr[i + 1] = incl; cursor[i] = incl - v; }
    if (base == 0 && t == 0) rowptr[0] = 0;
    __syncthreads();
    if (t == 0) carry_s += swsum[15];
    __syncthreads();
  }
}

__global__ void scatter_edges(const int* __restrict__ esrc, const int* __restrict__ edst,
                              int E, int Etot, int* __restrict__ cursor,
                              int* __restrict__ csr_src) {
  const int t = blockIdx.x * blockDim.x + threadIdx.x;
  if (t >= Etot) return;
  int s, d;
  if (t < E) { s = esrc[t]; d = edst[t]; } else { s = t - E; d = s; }
  const int pos = atomicAdd(&cursor[d], 1);
  csr_src[pos] = s;
}

// ---------------- wave-per-node softmax-weighted gather aggregate ----------------
template <int H, int C>
__global__ __launch_bounds__(256) void gat_agg_wave(
    const ushort* __restrict__ hb, const int* __restrict__ rowptr,
    const int* __restrict__ csr_src, const float* __restrict__ a_s,
    const float* __restrict__ a_d, const float* __restrict__ bias,
    ushort* __restrict__ outb, float act_slope, int Nn) {
  constexpr int HC = H * C;
  constexpr int NU = HC / 2;      // uints per row
  constexpr int PPT = NU / 128;   // uint2 per lane
  const int n = blockIdx.x * 4 + (threadIdx.x >> 6);
  const int lane = threadIdx.x & 63;
  if (n >= Nn) return;
  float ad_n[H];
#pragma unroll
  for (int h = 0; h < H; h++) ad_n[h] = a_d[n * H + h];
  const int start = rowptr[n], end = rowptr[n + 1];
  f32x4 acc[PPT];
#pragma unroll
  for (int q = 0; q < PPT; q++)
#pragma unroll
    for (int e = 0; e < 4; e++) acc[q][e] = 0.f;
  float den[H];
#pragma unroll
  for (int h = 0; h < H; h++) den[h] = 0.f;

  for (int base = start; base < end; base += 64) {
    const int cnt = min(64, end - base);
    int s = 0;
    float w[H];
#pragma unroll
    for (int h = 0; h < H; h++) w[h] = 0.f;
    if (lane < cnt) {
      s = csr_src[base + lane];
      float asv[H];
      if constexpr (H == 4) {
        const float4 t4 = *(const float4*)(a_s + s * 4);
        asv[0] = t4.x; asv[1] = t4.y; asv[2] = t4.z; asv[3] = t4.w;
      } else {
        asv[0] = a_s[s];
      }
#pragma unroll
      for (int h = 0; h < H; h++) {
        float lg = asv[h] + ad_n[h];
        lg = LRELU(lg, 0.2f);
        w[h] = __expf(lg);
        den[h] += w[h];
      }
    }
    for (int j = 0; j < cnt; j++) {
      const int sj = __shfl(s, j);
      float wj[H];
#pragma unroll
      for (int h = 0; h < H; h++) wj[h] = __shfl(w[h], j);
      const uint2* hp = (const uint2*)(hb + (size_t)sj * HC);
#pragma unroll
      for (int q = 0; q < PPT; q++) {
        const int pu = q * 128 + lane * 2;
        const uint2 v = hp[q * 64 + lane];
        const float wq = wj[(2 * pu) / C];
        acc[q][0] += wq * bflo(v.x);
        acc[q][1] += wq * bfhi(v.x);
        acc[q][2] += wq * bflo(v.y);
        acc[q][3] += wq * bfhi(v.y);
      }
    }
  }
#pragma unroll
  for (int h = 0; h < H; h++) {
#pragma unroll
    for (int off = 1; off < 64; off <<= 1) den[h] += __shfl_xor(den[h], off);
    den[h] = 1.f / den[h];
  }
#pragma unroll
  for (int q = 0; q < PPT; q++) {
    const int pu = q * 128 + lane * 2;
    const float iv = den[(2 * pu) / C];
    const float4 b4 = *(const float4*)(bias + 2 * pu);
    const float o0 = LRELU(acc[q][0] * iv + b4.x, act_slope);
    const float o1 = LRELU(acc[q][1] * iv + b4.y, act_slope);
    const float o2 = LRELU(acc[q][2] * iv + b4.z, act_slope);
    const float o3 = LRELU(acc[q][3] * iv + b4.w, act_slope);
    uint2 o;
    o.x = (uint)f2bf(o0) | ((uint)f2bf(o1) << 16);
    o.y = (uint)f2bf(o2) | ((uint)f2bf(o3) << 16);
    ((uint2*)outb)[(size_t)n * (NU / 2) + q * 64 + lane] = o;
  }
}

// ---------------- layer-3 aggregate (H=1,C=128) fused with head MLP ----------------
__global__ __launch_bounds__(64) void gat_agg3_mlp(
    const ushort* __restrict__ hb, const int* __restrict__ rowptr,
    const int* __restrict__ csr_src, const float* __restrict__ a_s,
    const float* __restrict__ a_d, const float* __restrict__ b3,
    const float* __restrict__ pw, const float* __restrict__ pb,
    const float* __restrict__ f1w, const float* __restrict__ f1b,
    const float* __restrict__ f2w, const float* __restrict__ f2b,
    float* __restrict__ out) {
  const int n = blockIdx.x;
  const int tid = threadIdx.x;
  __shared__ float sx[128];
  __shared__ float s1[16];
  __shared__ float s2[32];
  const float ad_n = a_d[n];
  const int start = rowptr[n], end = rowptr[n + 1];
  float2 acc = make_float2(0.f, 0.f);
  float den = 0.f;
  for (int base = start; base < end; base += 64) {
    const int cnt = min(64, end - base);
    int s = 0;
    float w = 0.f;
    if (tid < cnt) {
      s = csr_src[base + tid];
      float lg = a_s[s] + ad_n;
      lg = LRELU(lg, 0.2f);
      w = __expf(lg);
      den += w;
    }
    for (int j = 0; j < cnt; j++) {
      const int sj = __shfl(s, j);
      const float wj = __shfl(w, j);
      const uint v = ((const uint*)(hb + (size_t)sj * 128))[tid];
      acc.x += wj * bflo(v);
      acc.y += wj * bfhi(v);
    }
  }
#pragma unroll
  for (int off = 1; off < 64; off <<= 1) den += __shfl_xor(den, off);
  const float iv = 1.f / den;
  sx[2 * tid]     = LRELU(acc.x * iv + b3[2 * tid], 0.15f);
  sx[2 * tid + 1] = LRELU(acc.y * iv + b3[2 * tid + 1], 0.15f);
  __syncthreads();
  if (tid < 16) {
    float a = pb[tid];
    for (int c = 0; c < 128; c++) a += sx[c] * pw[c * 16 + tid];
    s1[tid] = a;
  }
  __syncthreads();
  if (tid < 32) {
    float a = f1b[tid];
    for (int c = 0; c < 16; c++) a += s1[c] * f1w[c * 32 + tid];
    s2[tid] = LRELU(a, 0.15f);
  }
  __syncthreads();
  if (tid < 2) {
    float a = f2b[tid];
    for (int c = 0; c < 32; c++) a += s2[c] * f2w[c * 2 + tid];
    out[(size_t)n * 2 + tid] = a;
  }
}

extern "C" void kernel_launch(void* const* d_in, const int* in_sizes, int n_in,
                              void* d_out, int out_size, void* d_ws, size_t ws_size,
                              hipStream_t stream) {
  const float* x   = (const float*)d_in[0];
  const int* ei    = (const int*)d_in[1];
  const float* W1  = (const float*)d_in[2];
  const float* as1 = (const float*)d_in[3];
  const float* ad1 = (const float*)d_in[4];
  const float* b1  = (const float*)d_in[5];
  const float* W2  = (const float*)d_in[6];
  const float* as2 = (const float*)d_in[7];
  const float* ad2 = (const float*)d_in[8];
  const float* b2  = (const float*)d_in[9];
  const float* W3  = (const float*)d_in[10];
  const float* as3 = (const float*)d_in[11];
  const float* ad3 = (const float*)d_in[12];
  const float* b3  = (const float*)d_in[13];
  const float* pw  = (const float*)d_in[14];
  const float* pb  = (const float*)d_in[15];
  const float* f1w = (const float*)d_in[16];
  const float* f1b = (const float*)d_in[17];
  const float* f2w = (const float*)d_in[18];
  const float* f2b = (const float*)d_in[19];
  float* out = (float*)d_out;

  const int N = in_sizes[0] / 1287;   // 20000
  const int E = in_sizes[1] / 2;      // 160000
  const int Etot = E + N;
  const int* esrc = ei;
  const int* edst = ei + E;
  const int K1 = 1287, K1p = 1312;

  char* ws = (char*)d_ws;
  size_t off = 0;
  auto alloc = [&](size_t bytes) -> void* {
    void* p = ws + off;
    off = (off + bytes + 255) & ~(size_t)255;
    return p;
  };
  ushort* hb  = (ushort*)alloc((size_t)N * 1024 * 2);
  ushort* ob  = (ushort*)alloc((size_t)N * 1024 * 2);
  ushort* xb  = (ushort*)alloc((size_t)N * K1p * 2);
  ushort* W1t = (ushort*)alloc((size_t)512 * K1p * 2);
  ushort* W2t = (ushort*)alloc((size_t)1024 * 512 * 2);
  ushort* W3t = (ushort*)alloc((size_t)128 * 1024 * 2);
  float* av   = (float*)alloc((size_t)N * 8 * sizeof(float));  // a_s then a_d
  int* deg    = (int*)alloc((size_t)N * sizeof(int));
  int* rowptr = (int*)alloc((size_t)(N + 1) * sizeof(int));
  int* cursor = (int*)alloc((size_t)N * sizeof(int));
  int* csr    = (int*)alloc((size_t)Etot * sizeof(int));
  float* asb = av;
  float* adb = av + (size_t)N * 4;

  // ---- CSR build ----
  hipMemsetAsync(deg, 0, (size_t)N * sizeof(int), stream);
  count_deg<<<(E + 255) / 256, 256, 0, stream>>>(edst, E, deg);
  scan_kernel<<<1, 1024, 0, stream>>>(deg, rowptr, cursor, N);
  scatter_edges<<<(Etot + 255) / 256, 256, 0, stream>>>(esrc, edst, E, Etot, cursor, csr);

  // ---- casts ----
  {
    const long long nx = (long long)N * (K1p / 4);
    cast_pad_rows<<<(int)((nx + 255) / 256), 256, 0, stream>>>(x, xb, N, K1, K1p);
    cast_W_T<<<dim3(K1p / 32, (512 + 31) / 32), dim3(32, 8), 0, stream>>>(W1, W1t, K1, 512, K1p);
    cast_W_T<<<dim3(512 / 32, 1024 / 32), dim3(32, 8), 0, stream>>>(W2, W2t, 512, 1024, 512);
    cast_W_T<<<dim3(1024 / 32, 128 / 32), dim3(32, 8), 0, stream>>>(W3, W3t, 1024, 128, 1024);
  }

  const int tilesM = (N + 127) / 128;  // 157
  const int aggBlocks = (N + 3) / 4;

  // ---- layer 1: 1287 -> 4x128, concat ----
  {
    const int H = 4, C = 128, HC = 512;
    hipMemsetAsync(av, 0, (size_t)N * 8 * sizeof(float), stream);
    gemm_bf16<<<tilesM * (HC / 128), 256, 0, stream>>>(xb, W1t, hb, N, HC, K1p,
                                                       as1, ad1, asb, adb, H, C);
    gat_agg_wave<4, 128><<<aggBlocks, 256, 0, stream>>>(hb, rowptr, csr, asb, adb,
                                                        b1, ob, 0.15f, N);
  }
  // ---- layer 2: 512 -> 4x256, concat ----
  {
    const int H = 4, C = 256, HC = 1024;
    hipMemsetAsync(av, 0, (size_t)N * 8 * sizeof(float), stream);
    gemm_bf16<<<tilesM * (HC / 128), 256, 0, stream>>>(ob, W2t, hb, N, HC, 512,
                                                       as2, ad2, asb, adb, H, C);
    gat_agg_wave<4, 256><<<aggBlocks, 256, 0, stream>>>(hb, rowptr, csr, asb, adb,
                                                        b2, ob, 0.15f, N);
  }
  // ---- layer 3: 1024 -> 128, 1 head + head MLP fused ----
  {
    const int HC = 128;
    hipMemsetAsync(av, 0, (size_t)N * 8 * sizeof(float), stream);
    gemm_bf16<<<tilesM * (HC / 128), 256, 0, stream>>>(ob, W3t, hb, N, HC, 1024,
                                                       as3, ad3, asb, adb, 1, 128);
    gat_agg3_mlp<<<N, 64, 0, stream>>>(hb, rowptr, csr, asb, adb, b3,
                                       pw, pb, f1w, f1b, f2w, f2b, out);
  }
}

// Round 6
// 525.638 us; speedup vs baseline: 1.0325x; 1.0325x over previous
//
#include <hip/hip_runtime.h>
#include <hip/hip_bf16.h>
#include <cstdint>
#include <cstddef>

#define LRELU(x, s) ((x) > 0.f ? (x) : (s) * (x))

typedef __attribute__((ext_vector_type(8))) short bf16x8;
typedef __attribute__((ext_vector_type(4))) float f32x4;

__device__ __forceinline__ float bflo(uint v) { return __uint_as_float(v << 16); }
__device__ __forceinline__ float bfhi(uint v) { return __uint_as_float(v & 0xffff0000u); }
__device__ __forceinline__ ushort f2bf(float f) {  // RTNE, finite inputs
  const uint u = __float_as_uint(f);
  return (ushort)((u + 0x7fffu + ((u >> 16) & 1u)) >> 16);
}

// async global->LDS copy, 16 B per lane; LDS dest = wave-uniform base + lane*16.
__device__ __forceinline__ void async16(const ushort* g, ushort* l) {
  __builtin_amdgcn_global_load_lds(
      (const __attribute__((address_space(1))) unsigned int*)g,
      (__attribute__((address_space(3))) unsigned int*)l, 16, 0, 0);
}

// s_waitcnt immediates: vmcnt in [3:0], expcnt=7 (no wait), lgkmcnt=15 (no wait)
#define WAITCNT_VM(n) (0xF70 | (n))

// ---------------- casts ----------------
__global__ void cast_pad_rows(const float* __restrict__ in, ushort* __restrict__ out,
                              int rows, int K, int Kp) {
  const int P4 = Kp >> 2;
  const long long idx = (long long)blockIdx.x * blockDim.x + threadIdx.x;
  if (idx >= (long long)rows * P4) return;
  const int r = (int)(idx / P4);
  const int c = ((int)(idx - (long long)r * P4)) << 2;
  const float* p = in + (size_t)r * K + c;
  float v0 = 0.f, v1 = 0.f, v2 = 0.f, v3 = 0.f;
  if (c + 3 < K) { v0 = p[0]; v1 = p[1]; v2 = p[2]; v3 = p[3]; }
  else {
    if (c + 0 < K) v0 = p[0];
    if (c + 1 < K) v1 = p[1];
    if (c + 2 < K) v2 = p[2];
    if (c + 3 < K) v3 = p[3];
  }
  uint2 o;
  o.x = (uint)f2bf(v0) | ((uint)f2bf(v1) << 16);
  o.y = (uint)f2bf(v2) | ((uint)f2bf(v3) << 16);
  *(uint2*)(out + (size_t)r * Kp + c) = o;
}

__global__ void cast_W_T(const float* __restrict__ W, ushort* __restrict__ Wt,
                         int K, int Nn, int Kp) {
  __shared__ float tile[32][33];
  const int kt = blockIdx.x * 32;
  const int nt = blockIdx.y * 32;
  const int tx = threadIdx.x;
  const int ty = threadIdx.y;
  for (int r = ty; r < 32; r += 8) {
    const int k = kt + r, nn = nt + tx;
    tile[r][tx] = (k < K && nn < Nn) ? W[(size_t)k * Nn + nn] : 0.f;
  }
  __syncthreads();
  for (int r = ty; r < 32; r += 8) {
    const int nn = nt + r, k = kt + tx;
    if (nn < Nn && k < Kp) Wt[(size_t)nn * Kp + k] = f2bf(tile[tx][r]);
  }
}

// ---------------- bf16 MFMA GEMM, 2-deep async pipeline + fused att-dot epilogue --------
// TM = 128 or 64 (row-tile). Col-tile fixed 128. BK=32.
template <int TM>
__global__ __launch_bounds__(256) void gemm_bf16(
    const ushort* __restrict__ A, const ushort* __restrict__ Bt, ushort* __restrict__ C,
    int M, int N, int Kp,
    const float* __restrict__ AS, const float* __restrict__ AD,
    float* __restrict__ asb, float* __restrict__ adb, int H, int headC) {
  constexpr int MI = TM / 32;            // mi-tiles per wave (4 or 2)
  constexpr int LPG = (TM == 128) ? 4 : 3;  // loads per group per lane
  __shared__ ushort sA[2 * TM * 32];
  __shared__ ushort sB[2 * 128 * 32];
  const int tid = threadIdx.x;
  const int wave = tid >> 6;
  const int lane = tid & 63;
  const int tilesN = N >> 7;
  const int bx = blockIdx.x % tilesN;
  const int by = blockIdx.x / tilesN;
  const int wrow = (wave >> 1) * (TM / 2);
  const int wcol = (wave & 1) * 64;
  const int quad = lane >> 4;
  const int ml = lane & 15;

  const int seg = (lane & 3) * 8;  // ushort k-offset within BK=32
  // B staging: wave covers rows [wave*32, wave*32+32) in two 16-row calls
  const int rB0 = wave * 32 + (lane >> 2);
  const int gB0 = bx * 128 + rB0;
  const ushort* pB0 = Bt + (size_t)gB0 * Kp + seg;
  const ushort* pB1 = Bt + (size_t)(gB0 + 16) * Kp + seg;
  ushort* lB0 = &sB[(wave * 32) * 32];
  ushort* lB1 = &sB[(wave * 32 + 16) * 32];
  // A staging
  const ushort *pA0, *pA1;
  ushort *lA0, *lA1;
  if constexpr (TM == 128) {
    const int r0 = wave * 32 + (lane >> 2);
    pA0 = A + (size_t)min(by * TM + r0, M - 1) * Kp + seg;
    pA1 = A + (size_t)min(by * TM + r0 + 16, M - 1) * Kp + seg;
    lA0 = &sA[(wave * 32) * 32];
    lA1 = &sA[(wave * 32 + 16) * 32];
  } else {
    const int r0 = wave * 16 + (lane >> 2);
    pA0 = A + (size_t)min(by * TM + r0, M - 1) * Kp + seg;
    pA1 = nullptr;
    lA0 = &sA[(wave * 16) * 32];
    lA1 = nullptr;
  }

  const int nIter = Kp >> 5;
  auto issue = [&](int it, int p) {
    const int k0 = it << 5;
    const int oa = p * TM * 32;
    const int ob_ = p * 128 * 32;
    async16(pA0 + k0, lA0 + oa);
    if constexpr (TM == 128) async16(pA1 + k0, lA1 + oa);
    async16(pB0 + k0, lB0 + ob_);
    async16(pB1 + k0, lB1 + ob_);
  };

  f32x4 acc[MI][4];
#pragma unroll
  for (int mi = 0; mi < MI; mi++)
#pragma unroll
    for (int ni = 0; ni < 4; ni++)
#pragma unroll
      for (int e = 0; e < 4; e++) acc[mi][ni][e] = 0.f;

  issue(0, 0);
  if (nIter > 1) issue(1, 1);
  int p = 0;
  for (int it = 0; it < nIter; ++it) {
    if (it + 1 < nIter) __builtin_amdgcn_s_waitcnt(WAITCNT_VM(LPG));
    else __builtin_amdgcn_s_waitcnt(WAITCNT_VM(0));
    __builtin_amdgcn_s_barrier();
    const ushort* bA = &sA[p * TM * 32];
    const ushort* bB = &sB[p * 128 * 32];
    bf16x8 af[MI], bfr[4];
#pragma unroll
    for (int mi = 0; mi < MI; mi++)
      af[mi] = *(const bf16x8*)&bA[(wrow + mi * 16 + ml) * 32 + quad * 8];
#pragma unroll
    for (int ni = 0; ni < 4; ni++)
      bfr[ni] = *(const bf16x8*)&bB[(wcol + ni * 16 + ml) * 32 + quad * 8];
#pragma unroll
    for (int mi = 0; mi < MI; mi++)
#pragma unroll
      for (int ni = 0; ni < 4; ni++)
        acc[mi][ni] = __builtin_amdgcn_mfma_f32_16x16x32_bf16(af[mi], bfr[ni], acc[mi][ni], 0, 0, 0);
    if (it + 2 < nIter) {
      __builtin_amdgcn_s_barrier();  // all waves done reading buf p
      issue(it + 2, p);
    }
    p ^= 1;
  }

  // C write (bf16)
#pragma unroll
  for (int mi = 0; mi < MI; mi++) {
#pragma unroll
    for (int r = 0; r < 4; r++) {
      const int row = by * TM + wrow + mi * 16 + quad * 4 + r;
      if (row < M) {
#pragma unroll
        for (int ni = 0; ni < 4; ni++) {
          const int col = bx * 128 + wcol + ni * 16 + ml;
          C[(size_t)row * N + col] = f2bf(acc[mi][ni][r]);
        }
      }
    }
  }

  // fused attention dots
  if (asb != nullptr) {
    float asv[4], adv[4];
#pragma unroll
    for (int ni = 0; ni < 4; ni++) {
      const int col = bx * 128 + wcol + ni * 16 + ml;
      asv[ni] = AS[col];
      adv[ni] = AD[col];
    }
    const int hh = (bx * 128 + wcol) / headC;  // wave-uniform (64-col span <= headC)
#pragma unroll
    for (int mi = 0; mi < MI; mi++) {
#pragma unroll
      for (int r = 0; r < 4; r++) {
        float ps = acc[mi][0][r] * asv[0] + acc[mi][1][r] * asv[1] +
                   acc[mi][2][r] * asv[2] + acc[mi][3][r] * asv[3];
        float pd = acc[mi][0][r] * adv[0] + acc[mi][1][r] * adv[1] +
                   acc[mi][2][r] * adv[2] + acc[mi][3][r] * adv[3];
#pragma unroll
        for (int off = 1; off < 16; off <<= 1) {
          ps += __shfl_xor(ps, off);
          pd += __shfl_xor(pd, off);
        }
        if (ml == 0) {
          const int row = by * TM + wrow + mi * 16 + quad * 4 + r;
          if (row < M) {
            atomicAdd(&asb[row * H + hh], ps);
            atomicAdd(&adb[row * H + hh], pd);
          }
        }
      }
    }
  }
}

// ---------------- CSR build ----------------
__global__ void count_deg(const int* __restrict__ dst, int E, int* __restrict__ deg) {
  const int t = blockIdx.x * blockDim.x + threadIdx.x;
  if (t < E) atomicAdd(&deg[dst[t]], 1);
}

__global__ __launch_bounds__(1024) void scan_kernel(const int* __restrict__ deg,
                                                    int* __restrict__ rowptr,
                                                    int* __restrict__ cursor, int n) {
  __shared__ int swsum[16];
  __shared__ int carry_s;
  const int t = threadIdx.x;
  const int wv = t >> 6, lane = t & 63;
  if (t == 0) carry_s = 0;
  __syncthreads();
  for (int base = 0; base < n; base += 1024) {
    const int i = base + t;
    const int v = (i < n) ? (deg[i] + 1) : 0;
    int sc = v;
#pragma unroll
    for (int off = 1; off < 64; off <<= 1) {
      const int u = __shfl_up(sc, off);
      if (lane >= off) sc += u;
    }
    if (lane == 63) swsum[wv] = sc;
    __syncthreads();
    if (t < 16) {
      int x = swsum[t];
#pragma unroll
      for (int off = 1; off < 16; off <<= 1) {
        const int u = __shfl_up(x, off);
        if (t >= off) x += u;
      }
      swsum[t] = x;
    }
    __syncthreads();
    const int incl = sc + (wv == 0 ? 0 : swsum[wv - 1]) + carry_s;
    if (i < n) { rowptr[i + 1] = incl; cursor[i] = incl - v; }
    if (base == 0 && t == 0) rowptr[0] = 0;
    __syncthreads();
    if (t == 0) carry_s += swsum[15];
    __syncthreads();
  }
}

__global__ void scatter_edges(const int* __restrict__ esrc, const int* __restrict__ edst,
                              int E, int Etot, int* __restrict__ cursor,
                              int* __restrict__ csr_src) {
  const int t = blockIdx.x * blockDim.x + threadIdx.x;
  if (t >= Etot) return;
  int s, d;
  if (t < E) { s = esrc[t]; d = edst[t]; } else { s = t - E; d = s; }
  const int pos = atomicAdd(&cursor[d], 1);
  csr_src[pos] = s;
}

// ---------------- wave-per-node softmax-weighted gather aggregate ----------------
template <int H, int C>
__global__ __launch_bounds__(256) void gat_agg_wave(
    const ushort* __restrict__ hb, const int* __restrict__ rowptr,
    const int* __restrict__ csr_src, const float* __restrict__ a_s,
    const float* __restrict__ a_d, const float* __restrict__ bias,
    ushort* __restrict__ outb, float act_slope, int Nn) {
  constexpr int HC = H * C;
  constexpr int NU = HC / 2;      // uints per row
  constexpr int PPT = NU / 128;   // uint2 per lane
  const int n = blockIdx.x * 4 + (threadIdx.x >> 6);
  const int lane = threadIdx.x & 63;
  if (n >= Nn) return;
  float ad_n[H];
#pragma unroll
  for (int h = 0; h < H; h++) ad_n[h] = a_d[n * H + h];
  const int start = rowptr[n], end = rowptr[n + 1];
  f32x4 acc[PPT];
#pragma unroll
  for (int q = 0; q < PPT; q++)
#pragma unroll
    for (int e = 0; e < 4; e++) acc[q][e] = 0.f;
  float den[H];
#pragma unroll
  for (int h = 0; h < H; h++) den[h] = 0.f;

  for (int base = start; base < end; base += 64) {
    const int cnt = min(64, end - base);
    int s = 0;
    float w[H];
#pragma unroll
    for (int h = 0; h < H; h++) w[h] = 0.f;
    if (lane < cnt) {
      s = csr_src[base + lane];
      float asv[H];
      if constexpr (H == 4) {
        const float4 t4 = *(const float4*)(a_s + s * 4);
        asv[0] = t4.x; asv[1] = t4.y; asv[2] = t4.z; asv[3] = t4.w;
      } else {
        asv[0] = a_s[s];
      }
#pragma unroll
      for (int h = 0; h < H; h++) {
        float lg = asv[h] + ad_n[h];
        lg = LRELU(lg, 0.2f);
        w[h] = __expf(lg);
        den[h] += w[h];
      }
    }
    for (int j = 0; j < cnt; j++) {
      const int sj = __shfl(s, j);
      float wj[H];
#pragma unroll
      for (int h = 0; h < H; h++) wj[h] = __shfl(w[h], j);
      const uint2* hp = (const uint2*)(hb + (size_t)sj * HC);
#pragma unroll
      for (int q = 0; q < PPT; q++) {
        const int pu = q * 128 + lane * 2;
        const uint2 v = hp[q * 64 + lane];
        const float wq = wj[(2 * pu) / C];
        acc[q][0] += wq * bflo(v.x);
        acc[q][1] += wq * bfhi(v.x);
        acc[q][2] += wq * bflo(v.y);
        acc[q][3] += wq * bfhi(v.y);
      }
    }
  }
#pragma unroll
  for (int h = 0; h < H; h++) {
#pragma unroll
    for (int off = 1; off < 64; off <<= 1) den[h] += __shfl_xor(den[h], off);
    den[h] = 1.f / den[h];
  }
#pragma unroll
  for (int q = 0; q < PPT; q++) {
    const int pu = q * 128 + lane * 2;
    const float iv = den[(2 * pu) / C];
    const float4 b4 = *(const float4*)(bias + 2 * pu);
    const float o0 = LRELU(acc[q][0] * iv + b4.x, act_slope);
    const float o1 = LRELU(acc[q][1] * iv + b4.y, act_slope);
    const float o2 = LRELU(acc[q][2] * iv + b4.z, act_slope);
    const float o3 = LRELU(acc[q][3] * iv + b4.w, act_slope);
    uint2 o;
    o.x = (uint)f2bf(o0) | ((uint)f2bf(o1) << 16);
    o.y = (uint)f2bf(o2) | ((uint)f2bf(o3) << 16);
    ((uint2*)outb)[(size_t)n * (NU / 2) + q * 64 + lane] = o;
  }
}

// ---------------- layer-3 aggregate (H=1,C=128) fused with head MLP ----------------
__global__ __launch_bounds__(64) void gat_agg3_mlp(
    const ushort* __restrict__ hb, const int* __restrict__ rowptr,
    const int* __restrict__ csr_src, const float* __restrict__ a_s,
    const float* __restrict__ a_d, const float* __restrict__ b3,
    const float* __restrict__ pw, const float* __restrict__ pb,
    const float* __restrict__ f1w, const float* __restrict__ f1b,
    const float* __restrict__ f2w, const float* __restrict__ f2b,
    float* __restrict__ out) {
  const int n = blockIdx.x;
  const int tid = threadIdx.x;
  __shared__ float sx[128];
  __shared__ float s1[16];
  __shared__ float s2[32];
  const float ad_n = a_d[n];
  const int start = rowptr[n], end = rowptr[n + 1];
  float2 acc = make_float2(0.f, 0.f);
  float den = 0.f;
  for (int base = start; base < end; base += 64) {
    const int cnt = min(64, end - base);
    int s = 0;
    float w = 0.f;
    if (tid < cnt) {
      s = csr_src[base + tid];
      float lg = a_s[s] + ad_n;
      lg = LRELU(lg, 0.2f);
      w = __expf(lg);
      den += w;
    }
    for (int j = 0; j < cnt; j++) {
      const int sj = __shfl(s, j);
      const float wj = __shfl(w, j);
      const uint v = ((const uint*)(hb + (size_t)sj * 128))[tid];
      acc.x += wj * bflo(v);
      acc.y += wj * bfhi(v);
    }
  }
#pragma unroll
  for (int off = 1; off < 64; off <<= 1) den += __shfl_xor(den, off);
  const float iv = 1.f / den;
  sx[2 * tid]     = LRELU(acc.x * iv + b3[2 * tid], 0.15f);
  sx[2 * tid + 1] = LRELU(acc.y * iv + b3[2 * tid + 1], 0.15f);
  __syncthreads();
  if (tid < 16) {
    float a = pb[tid];
    for (int c = 0; c < 128; c++) a += sx[c] * pw[c * 16 + tid];
    s1[tid] = a;
  }
  __syncthreads();
  if (tid < 32) {
    float a = f1b[tid];
    for (int c = 0; c < 16; c++) a += s1[c] * f1w[c * 32 + tid];
    s2[tid] = LRELU(a, 0.15f);
  }
  __syncthreads();
  if (tid < 2) {
    float a = f2b[tid];
    for (int c = 0; c < 32; c++) a += s2[c] * f2w[c * 2 + tid];
    out[(size_t)n * 2 + tid] = a;
  }
}

extern "C" void kernel_launch(void* const* d_in, const int* in_sizes, int n_in,
                              void* d_out, int out_size, void* d_ws, size_t ws_size,
                              hipStream_t stream) {
  const float* x   = (const float*)d_in[0];
  const int* ei    = (const int*)d_in[1];
  const float* W1  = (const float*)d_in[2];
  const float* as1 = (const float*)d_in[3];
  const float* ad1 = (const float*)d_in[4];
  const float* b1  = (const float*)d_in[5];
  const float* W2  = (const float*)d_in[6];
  const float* as2 = (const float*)d_in[7];
  const float* ad2 = (const float*)d_in[8];
  const float* b2  = (const float*)d_in[9];
  const float* W3  = (const float*)d_in[10];
  const float* as3 = (const float*)d_in[11];
  const float* ad3 = (const float*)d_in[12];
  const float* b3  = (const float*)d_in[13];
  const float* pw  = (const float*)d_in[14];
  const float* pb  = (const float*)d_in[15];
  const float* f1w = (const float*)d_in[16];
  const float* f1b = (const float*)d_in[17];
  const float* f2w = (const float*)d_in[18];
  const float* f2b = (const float*)d_in[19];
  float* out = (float*)d_out;

  const int N = in_sizes[0] / 1287;   // 20000
  const int E = in_sizes[1] / 2;      // 160000
  const int Etot = E + N;
  const int* esrc = ei;
  const int* edst = ei + E;
  const int K1 = 1287, K1p = 1312;

  char* ws = (char*)d_ws;
  size_t off = 0;
  auto alloc = [&](size_t bytes) -> void* {
    void* p = ws + off;
    off = (off + bytes + 255) & ~(size_t)255;
    return p;
  };
  ushort* hb  = (ushort*)alloc((size_t)N * 1024 * 2);
  ushort* ob  = (ushort*)alloc((size_t)N * 1024 * 2);
  ushort* xb  = (ushort*)alloc((size_t)N * K1p * 2);
  ushort* W1t = (ushort*)alloc((size_t)512 * K1p * 2);
  ushort* W2t = (ushort*)alloc((size_t)1024 * 512 * 2);
  ushort* W3t = (ushort*)alloc((size_t)128 * 1024 * 2);
  float* av   = (float*)alloc((size_t)N * 8 * sizeof(float));  // a_s then a_d
  int* deg    = (int*)alloc((size_t)N * sizeof(int));
  int* rowptr = (int*)alloc((size_t)(N + 1) * sizeof(int));
  int* cursor = (int*)alloc((size_t)N * sizeof(int));
  int* csr    = (int*)alloc((size_t)Etot * sizeof(int));
  float* asb = av;
  float* adb = av + (size_t)N * 4;

  // ---- CSR build ----
  hipMemsetAsync(deg, 0, (size_t)N * sizeof(int), stream);
  count_deg<<<(E + 255) / 256, 256, 0, stream>>>(edst, E, deg);
  scan_kernel<<<1, 1024, 0, stream>>>(deg, rowptr, cursor, N);
  scatter_edges<<<(Etot + 255) / 256, 256, 0, stream>>>(esrc, edst, E, Etot, cursor, csr);

  // ---- casts ----
  {
    const long long nx = (long long)N * (K1p / 4);
    cast_pad_rows<<<(int)((nx + 255) / 256), 256, 0, stream>>>(x, xb, N, K1, K1p);
    cast_W_T<<<dim3(K1p / 32, (512 + 31) / 32), dim3(32, 8), 0, stream>>>(W1, W1t, K1, 512, K1p);
    cast_W_T<<<dim3(512 / 32, 1024 / 32), dim3(32, 8), 0, stream>>>(W2, W2t, 512, 1024, 512);
    cast_W_T<<<dim3(1024 / 32, 128 / 32), dim3(32, 8), 0, stream>>>(W3, W3t, 1024, 128, 1024);
  }

  const int tilesM = (N + 127) / 128;    // 157
  const int tilesM64 = (N + 63) / 64;    // 313
  const int aggBlocks = (N + 3) / 4;

  // ---- layer 1: 1287 -> 4x128, concat ----
  {
    const int H = 4, C = 128, HC = 512;
    hipMemsetAsync(av, 0, (size_t)N * 8 * sizeof(float), stream);
    gemm_bf16<128><<<tilesM * (HC / 128), 256, 0, stream>>>(xb, W1t, hb, N, HC, K1p,
                                                            as1, ad1, asb, adb, H, C);
    gat_agg_wave<4, 128><<<aggBlocks, 256, 0, stream>>>(hb, rowptr, csr, asb, adb,
                                                        b1, ob, 0.15f, N);
  }
  // ---- layer 2: 512 -> 4x256, concat ----
  {
    const int H = 4, C = 256, HC = 1024;
    hipMemsetAsync(av, 0, (size_t)N * 8 * sizeof(float), stream);
    gemm_bf16<128><<<tilesM * (HC / 128), 256, 0, stream>>>(ob, W2t, hb, N, HC, 512,
                                                            as2, ad2, asb, adb, H, C);
    gat_agg_wave<4, 256><<<aggBlocks, 256, 0, stream>>>(hb, rowptr, csr, asb, adb,
                                                        b2, ob, 0.15f, N);
  }
  // ---- layer 3: 1024 -> 128, 1 head + head MLP fused ----
  {
    const int HC = 128;
    hipMemsetAsync(av, 0, (size_t)N * 8 * sizeof(float), stream);
    gemm_bf16<64><<<tilesM64 * (HC / 128), 256, 0, stream>>>(ob, W3t, hb, N, HC, 1024,
                                                             as3, ad3, asb, adb, 1, 128);
    gat_agg3_mlp<<<N, 64, 0, stream>>>(hb, rowptr, csr, asb, adb, b3,
                                       pw, pb, f1w, f1b, f2w, f2b, out);
  }
}